// Round 9
// baseline (131.493 us; speedup 1.0000x reference)
//
#include <hip/hip_runtime.h>
#include <math.h>

#define LEV_MAX 256   // n_levels = 155 for bits=8,k=2,signed

// Model (from rounds 0-8 evidence):
//   a  = f32 grad-scale(alpha) (= alpha when alpha dyadic, e.g. 5.375)
//   xc = clip(x, -a, a)                                (f32)
//   xn = xc * fl(1/a)      <- XLA reciprocal-multiply, NOT x/a
//   searchsorted(levels, xn, 'left') + |xn-l0|>|xn-l1| pick (f32)
//   out = q*a + (x - xc)   <- pass-through tail beyond clip (max|ref|>a!)
__global__ __launch_bounds__(256) void apot_quant_kernel(
    const float* __restrict__ x,
    const float* __restrict__ alpha_p,
    const float* __restrict__ levels,
    float* __restrict__ out,
    int n_levels, long long n_elem, float g)
{
#pragma clang fp contract(off)
    __shared__ float s_lev[LEV_MAX];
    const int t = threadIdx.x;
    for (int i = t; i < LEV_MAX; i += blockDim.x)
        s_lev[i] = (i < n_levels) ? levels[i] : 3.0e38f;
    __syncthreads();

    // a = max((alpha - alpha*g) + alpha*g, EPS), each op f32-rounded, no fma.
    const float alpha = alpha_p[0];
    const float ag = __fmul_rn(alpha, g);
    const float a  = fmaxf(__fadd_rn(__fsub_rn(alpha, ag), ag), 1e-8f);
    // XLA rewrites x/ broadcast(a) into x * (1/a): one correctly-rounded
    // f32 divide for the reciprocal, then per-element multiply.
    const float r = 1.0f / a;
    const int nm1 = n_levels - 1;

    const long long nvec = n_elem >> 2;
    const long long gid = (long long)blockIdx.x * blockDim.x + t;
    const long long stride = (long long)gridDim.x * blockDim.x;

    for (long long idx = gid; idx < nvec; idx += stride) {
        float4 xv = reinterpret_cast<const float4*>(x)[idx];
        float4 ov;
        float* xs = &xv.x;
        float* os = &ov.x;
        #pragma unroll
        for (int e = 0; e < 4; ++e) {
            const float xe = xs[e];
            const float xc = fminf(fmaxf(xe, -a), a);
            const float xn = __fmul_rn(xc, r);      // reciprocal-multiply
            // searchsorted(levels, xn, 'left'): branchless lower_bound,
            // 8 fixed steps (2^8 >= n_levels=155)
            int lo = 0, hi = n_levels;
            #pragma unroll
            for (int it = 0; it < 8; ++it) {
                int mid = (lo + hi) >> 1;
                bool c = s_lev[mid] < xn;
                lo = c ? mid + 1 : lo;
                hi = c ? hi : mid;
            }
            int p0 = min(max(lo - 1, 0), nm1);
            int p1 = min(lo, nm1);
            float l0 = s_lev[p0];
            float l1 = s_lev[p1];
            float q = (fabsf(xn - l0) > fabsf(xn - l1)) ? l1 : l0;  // tie -> l0
            // out = q*a + (x - xc): equals q*a for |x|<=a (x-xc==0 exactly),
            // equals x beyond the clip (pass-through STE tail).
            os[e] = __fadd_rn(__fmul_rn(q, a), __fsub_rn(xe, xc));
        }
        reinterpret_cast<float4*>(out)[idx] = ov;
    }

    // Scalar tail (n_elem % 4), usually empty
    for (long long i = (nvec << 2) + gid; i < n_elem; i += stride) {
        const float xe = x[i];
        const float xc = fminf(fmaxf(xe, -a), a);
        const float xn = __fmul_rn(xc, r);
        int lo = 0, hi = n_levels;
        for (int it = 0; it < 8; ++it) {
            int mid = (lo + hi) >> 1;
            bool c = s_lev[mid] < xn;
            lo = c ? mid + 1 : lo;
            hi = c ? hi : mid;
        }
        int p0 = min(max(lo - 1, 0), nm1);
        int p1 = min(lo, nm1);
        float l0 = s_lev[p0];
        float l1 = s_lev[p1];
        float q = (fabsf(xn - l0) > fabsf(xn - l1)) ? l1 : l0;
        out[i] = __fadd_rn(__fmul_rn(q, a), __fsub_rn(xe, xc));
    }
}

extern "C" void kernel_launch(void* const* d_in, const int* in_sizes, int n_in,
                              void* d_out, int out_size, void* d_ws, size_t ws_size,
                              hipStream_t stream) {
    const float* x      = (const float*)d_in[0];
    const float* alpha  = (const float*)d_in[1];
    const float* levels = (const float*)d_in[2];
    float* out = (float*)d_out;

    const long long n_elem = (long long)in_sizes[0];
    const int n_levels = in_sizes[2];
    // g = 1/sqrt(numel); n = 2^26 -> exactly 2^-13
    const float g = (float)(1.0 / sqrt((double)n_elem));

    const int block = 256;
    long long nvec = n_elem >> 2;
    long long want = (nvec + block - 1) / block;
    int grid = (int)(want < 2048 ? (want > 0 ? want : 1) : 2048);

    apot_quant_kernel<<<grid, block, 0, stream>>>(x, alpha, levels, out,
                                                  n_levels, n_elem, g);
}

// Round 10
// 121.094 us; speedup vs baseline: 1.0859x; 1.0859x over previous
//
#include <hip/hip_runtime.h>
#include <math.h>

#define LEV_N   155   // n_levels for bits=8,k=2,signed
#define NPOS    78    // nonneg levels: 0 + 77 positive
#define PPAD    128   // padded positive table (pad = +huge)
#define NGRID   11    // register comparators sP[0,8,...,80]

// ---- fast path: symmetric half-table search, bit-exact vs R9 pipeline ----
// Equivalence (proved per-case incl. ties, +-0, |xn|>1, exact level hits):
//   signed searchsorted-left + (|xn-l0|>|xn-l1| ? l1 : l0)
// == mirrored lower_bound over P=levels[77:], candidates P[LB-1],P[LB],
//    pick_upper = (d0 > d1) for xn>=0, (d0 >= d1) for xn<0, then re-sign.
__device__ __forceinline__ float quant_one(
    float xe, float a, float r,
    const float* __restrict__ sP,
    const float2* __restrict__ sPair,
    const float R[NGRID])
{
#pragma clang fp contract(off)
    const float xc = fminf(fmaxf(xe, -a), a);
    const float xn = __fmul_rn(xc, r);      // reciprocal-multiply (== ref)
    const float y  = fabsf(xn);
    const bool  neg = (xn < 0.0f);
    // coarse: c = #{k : P[8k] < y}  (independent register compares, no LDS)
    int c = 0;
    #pragma unroll
    for (int k = 0; k < NGRID; ++k) c += (R[k] < y) ? 1 : 0;
    // lo = last index with sP[lo] < y; start of 8-wide window (sentinel -1)
    int lo = max(8 * c - 8, -1);
    int mid = lo + 4; lo = (sP[mid] < y) ? mid : lo;   // 3 LDS refine steps
    mid = lo + 2;     lo = (sP[mid] < y) ? mid : lo;
    mid = lo + 1;     lo = (sP[mid] < y) ? mid : lo;
    // LB = lo+1 in [0,78]; pair table gives clamped (P[LB-1], P[LB])
    const float2 pr = sPair[lo + 1];
    const float d0 = fabsf(__fsub_rn(y, pr.x));        // == ref |xn-l0| bits
    const float d1 = fabsf(__fsub_rn(pr.y, y));        // == ref |xn-l1| bits
    const bool up = neg ? (d0 >= d1) : (d0 > d1);      // tie dir per sign
    const float qm = up ? pr.y : pr.x;
    const float q  = neg ? -qm : qm;
    return __fadd_rn(__fmul_rn(q, a), __fsub_rn(xe, xc));
}

__global__ __launch_bounds__(256) void apot_quant_fast(
    const float* __restrict__ x,
    const float* __restrict__ alpha_p,
    const float* __restrict__ levels,
    float* __restrict__ out,
    long long n_elem, float g)
{
#pragma clang fp contract(off)
    __shared__ float  sP[PPAD];
    __shared__ float2 sPair[NPOS + 1];
    const int t = threadIdx.x;
    for (int i = t; i < PPAD; i += blockDim.x)
        sP[i] = (i < NPOS) ? levels[(LEV_N - NPOS) + i] : 3.0e38f;
    __syncthreads();
    if (t <= NPOS) {
        int j0 = max(t - 1, 0);
        int j1 = min(t, NPOS - 1);
        sPair[t] = make_float2(sP[j0], sP[j1]);
    }
    float R[NGRID];
    #pragma unroll
    for (int k = 0; k < NGRID; ++k) R[k] = sP[8 * k];  // broadcast reads
    __syncthreads();

    // a = max((alpha - alpha*g) + alpha*g, EPS), f32 ops, no contraction
    const float alpha = alpha_p[0];
    const float ag = __fmul_rn(alpha, g);
    const float a  = fmaxf(__fadd_rn(__fsub_rn(alpha, ag), ag), 1e-8f);
    const float r  = 1.0f / a;

    const long long nvec = n_elem >> 2;
    const long long gid = (long long)blockIdx.x * blockDim.x + t;
    const long long stride = (long long)gridDim.x * blockDim.x;

    for (long long idx = gid; idx < nvec; idx += stride) {
        float4 xv = reinterpret_cast<const float4*>(x)[idx];
        float4 ov;
        ov.x = quant_one(xv.x, a, r, sP, sPair, R);
        ov.y = quant_one(xv.y, a, r, sP, sPair, R);
        ov.z = quant_one(xv.z, a, r, sP, sPair, R);
        ov.w = quant_one(xv.w, a, r, sP, sPair, R);
        reinterpret_cast<float4*>(out)[idx] = ov;
    }
    for (long long i = (nvec << 2) + gid; i < n_elem; i += stride)
        out[i] = quant_one(x[i], a, r, sP, sPair, R);
}

// ---- fallback: proven R9 kernel (absmax 0.0), used if n_levels != 155 ----
#define LEV_MAX 256
__global__ __launch_bounds__(256) void apot_quant_kernel(
    const float* __restrict__ x,
    const float* __restrict__ alpha_p,
    const float* __restrict__ levels,
    float* __restrict__ out,
    int n_levels, long long n_elem, float g)
{
#pragma clang fp contract(off)
    __shared__ float s_lev[LEV_MAX];
    const int t = threadIdx.x;
    for (int i = t; i < LEV_MAX; i += blockDim.x)
        s_lev[i] = (i < n_levels) ? levels[i] : 3.0e38f;
    __syncthreads();
    const float alpha = alpha_p[0];
    const float ag = __fmul_rn(alpha, g);
    const float a  = fmaxf(__fadd_rn(__fsub_rn(alpha, ag), ag), 1e-8f);
    const float r = 1.0f / a;
    const int nm1 = n_levels - 1;
    const long long gid = (long long)blockIdx.x * blockDim.x + t;
    const long long stride = (long long)gridDim.x * blockDim.x;
    for (long long i = gid; i < n_elem; i += stride) {
        const float xe = x[i];
        const float xc = fminf(fmaxf(xe, -a), a);
        const float xn = __fmul_rn(xc, r);
        int lo = 0, hi = n_levels;
        for (int it = 0; it < 8; ++it) {
            int mid = (lo + hi) >> 1;
            bool cc = s_lev[mid] < xn;
            lo = cc ? mid + 1 : lo;
            hi = cc ? hi : mid;
        }
        int p0 = min(max(lo - 1, 0), nm1);
        int p1 = min(lo, nm1);
        float l0 = s_lev[p0];
        float l1 = s_lev[p1];
        float q = (fabsf(__fsub_rn(xn, l0)) > fabsf(__fsub_rn(xn, l1))) ? l1 : l0;
        out[i] = __fadd_rn(__fmul_rn(q, a), __fsub_rn(xe, xc));
    }
}

extern "C" void kernel_launch(void* const* d_in, const int* in_sizes, int n_in,
                              void* d_out, int out_size, void* d_ws, size_t ws_size,
                              hipStream_t stream) {
    const float* x      = (const float*)d_in[0];
    const float* alpha  = (const float*)d_in[1];
    const float* levels = (const float*)d_in[2];
    float* out = (float*)d_out;

    const long long n_elem = (long long)in_sizes[0];
    const int n_levels = in_sizes[2];
    const float g = (float)(1.0 / sqrt((double)n_elem));

    const int block = 256;
    if (n_levels == LEV_N) {
        long long nvec = n_elem >> 2;
        long long want = (nvec + block - 1) / block;
        int grid = (int)(want < 2048 ? (want > 0 ? want : 1) : 2048);
        apot_quant_fast<<<grid, block, 0, stream>>>(x, alpha, levels, out,
                                                    n_elem, g);
    } else {
        long long want = (n_elem + block - 1) / block;
        int grid = (int)(want < 2048 ? (want > 0 ? want : 1) : 2048);
        apot_quant_kernel<<<grid, block, 0, stream>>>(x, alpha, levels, out,
                                                      n_levels, n_elem, g);
    }
}

// Round 11
// 109.549 us; speedup vs baseline: 1.2003x; 1.1054x over previous
//
#include <hip/hip_runtime.h>
#include <math.h>

#define LEV_N  155    // n_levels for bits=8,k=2,signed
#define NPOS   78     // nonneg levels: 0 + 77 positive
#define NBUCK  4096   // uniform buckets over y in [0,1); width 2^-12 <= min midpoint spacing
#define BW     (1.0f / 4096.0f)

// Per element (proven bit-exact vs reference in R9/R10):
//   xc = clamp(x,-a,a); xn = xc * fl(1/a); y = |xn|; neg = xn<0
//   bucket b = floor(y*4096) (exact, pow2); j = sJ[b]; pair = sPair[j]
//   d0=|y-pr.x|, d1=|pr.y-y|; up = neg ? d0>=d1 : d0>d1; q = sign(pr[up])
//   out = q*a + (x-xc)
// j(b) = 1 + #(midpoints < b*BW): for a bucket inside one Voronoi cell either
// adjacent pair gives the same pick (margins >= 2^-13 vs 2^-24 rounding);
// for a straddle bucket the pair equals the reference's searchsorted pair,
// including at exact-tie points. So outputs match the reference bit-for-bit.
__device__ __forceinline__ float quant_one(
    float xe, float a, float r,
    const float2* __restrict__ sPair,
    const unsigned char* __restrict__ sJ)
{
#pragma clang fp contract(off)
    const float xc = fminf(fmaxf(xe, -a), a);
    const float xn = __fmul_rn(xc, r);          // reciprocal-multiply (== ref)
    const float y  = fabsf(xn);
    const bool  neg = (xn < 0.0f);
    const float u = __fmul_rn(y, 4096.0f);      // exact (power-of-two scale)
    int b = (int)u;                              // trunc == floor (y >= 0)
    b = min(b, NBUCK - 1);
    const int j = sJ[b];
    const float2 pr = sPair[j];
    const float d0 = fabsf(__fsub_rn(y, pr.x));  // == ref |xn-l0| bits
    const float d1 = fabsf(__fsub_rn(pr.y, y));  // == ref |xn-l1| bits
    const bool up = neg ? (d0 >= d1) : (d0 > d1);
    const float qm = up ? pr.y : pr.x;
    const float q  = neg ? -qm : qm;
    return __fadd_rn(__fmul_rn(q, a), __fsub_rn(xe, xc));
}

__global__ __launch_bounds__(256) void apot_quant_lut(
    const float* __restrict__ x,
    const float* __restrict__ alpha_p,
    const float* __restrict__ levels,
    float* __restrict__ out,
    long long n_elem, float g)
{
#pragma clang fp contract(off)
    __shared__ float  sP[NPOS];
    __shared__ float  sM[NPOS];          // midpoints m[0..76] + huge pad at [77]
    __shared__ float2 sPair[NPOS + 1];   // clamped consecutive pairs, idx 0..78
    __shared__ unsigned char sJ[NBUCK];  // bucket -> pair index j in [1,78]

    const int t = threadIdx.x;
    if (t < NPOS) sP[t] = levels[(LEV_N - NPOS) + t];
    __syncthreads();
    if (t < NPOS - 1)
        sM[t] = __fmul_rn(__fadd_rn(sP[t], sP[t + 1]), 0.5f);  // exact in f32
    if (t == NPOS - 1) sM[t] = 3.0e38f;
    if (t <= NPOS) {
        int j0 = max(t - 1, 0);
        int j1 = min(t, NPOS - 1);
        sPair[t] = make_float2(sP[j0], sP[j1]);
    }
    __syncthreads();

    // Build sJ: monotone walk, 16 buckets per thread.
    {
        const int b0 = t * (NBUCK / 256);
        const float s0 = (float)b0 * BW;             // exact
        int lo = 0, hi = NPOS - 1;                   // count over m[0..76]
        #pragma unroll
        for (int it = 0; it < 7; ++it) {             // cnt = #(m < s0)
            int mid = (lo + hi) >> 1;
            bool c = sM[mid] < s0;
            lo = c ? mid + 1 : lo;
            hi = c ? hi : mid;
        }
        int cnt = lo;
        for (int k = 0; k < NBUCK / 256; ++k) {
            float s = (float)(b0 + k) * BW;          // exact
            while (cnt < NPOS - 1 && sM[cnt] < s) ++cnt;
            sJ[b0 + k] = (unsigned char)(cnt + 1);
        }
    }
    __syncthreads();

    // a = max((alpha - alpha*g) + alpha*g, EPS), f32 ops, no contraction
    const float alpha = alpha_p[0];
    const float ag = __fmul_rn(alpha, g);
    const float a  = fmaxf(__fadd_rn(__fsub_rn(alpha, ag), ag), 1e-8f);
    const float r  = 1.0f / a;

    const long long nvec = n_elem >> 2;
    const long long gid = (long long)blockIdx.x * blockDim.x + t;
    const long long stride = (long long)gridDim.x * blockDim.x;

    for (long long idx = gid; idx < nvec; idx += stride) {
        float4 xv = reinterpret_cast<const float4*>(x)[idx];
        float4 ov;
        ov.x = quant_one(xv.x, a, r, sPair, sJ);
        ov.y = quant_one(xv.y, a, r, sPair, sJ);
        ov.z = quant_one(xv.z, a, r, sPair, sJ);
        ov.w = quant_one(xv.w, a, r, sPair, sJ);
        reinterpret_cast<float4*>(out)[idx] = ov;
    }
    for (long long i = (nvec << 2) + gid; i < n_elem; i += stride)
        out[i] = quant_one(x[i], a, r, sPair, sJ);
}

// ---- fallback: proven R9 kernel (absmax 0.0), used if n_levels != 155 ----
#define LEV_MAX 256
__global__ __launch_bounds__(256) void apot_quant_kernel(
    const float* __restrict__ x,
    const float* __restrict__ alpha_p,
    const float* __restrict__ levels,
    float* __restrict__ out,
    int n_levels, long long n_elem, float g)
{
#pragma clang fp contract(off)
    __shared__ float s_lev[LEV_MAX];
    const int t = threadIdx.x;
    for (int i = t; i < LEV_MAX; i += blockDim.x)
        s_lev[i] = (i < n_levels) ? levels[i] : 3.0e38f;
    __syncthreads();
    const float alpha = alpha_p[0];
    const float ag = __fmul_rn(alpha, g);
    const float a  = fmaxf(__fadd_rn(__fsub_rn(alpha, ag), ag), 1e-8f);
    const float r = 1.0f / a;
    const int nm1 = n_levels - 1;
    const long long gid = (long long)blockIdx.x * blockDim.x + t;
    const long long stride = (long long)gridDim.x * blockDim.x;
    for (long long i = gid; i < n_elem; i += stride) {
        const float xe = x[i];
        const float xc = fminf(fmaxf(xe, -a), a);
        const float xn = __fmul_rn(xc, r);
        int lo = 0, hi = n_levels;
        for (int it = 0; it < 8; ++it) {
            int mid = (lo + hi) >> 1;
            bool cc = s_lev[mid] < xn;
            lo = cc ? mid + 1 : lo;
            hi = cc ? hi : mid;
        }
        int p0 = min(max(lo - 1, 0), nm1);
        int p1 = min(lo, nm1);
        float l0 = s_lev[p0];
        float l1 = s_lev[p1];
        float q = (fabsf(__fsub_rn(xn, l0)) > fabsf(__fsub_rn(xn, l1))) ? l1 : l0;
        out[i] = __fadd_rn(__fmul_rn(q, a), __fsub_rn(xe, xc));
    }
}

extern "C" void kernel_launch(void* const* d_in, const int* in_sizes, int n_in,
                              void* d_out, int out_size, void* d_ws, size_t ws_size,
                              hipStream_t stream) {
    const float* x      = (const float*)d_in[0];
    const float* alpha  = (const float*)d_in[1];
    const float* levels = (const float*)d_in[2];
    float* out = (float*)d_out;

    const long long n_elem = (long long)in_sizes[0];
    const int n_levels = in_sizes[2];
    const float g = (float)(1.0 / sqrt((double)n_elem));

    const int block = 256;
    if (n_levels == LEV_N) {
        long long nvec = n_elem >> 2;
        long long want = (nvec + block - 1) / block;
        int grid = (int)(want < 2048 ? (want > 0 ? want : 1) : 2048);
        apot_quant_lut<<<grid, block, 0, stream>>>(x, alpha, levels, out,
                                                   n_elem, g);
    } else {
        long long want = (n_elem + block - 1) / block;
        int grid = (int)(want < 2048 ? (want > 0 ? want : 1) : 2048);
        apot_quant_kernel<<<grid, block, 0, stream>>>(x, alpha, levels, out,
                                                      n_levels, n_elem, g);
    }
}

// Round 13
// 107.258 us; speedup vs baseline: 1.2260x; 1.0214x over previous
//
#include <hip/hip_runtime.h>
#include <math.h>

#define LEV_N  155    // n_levels for bits=8,k=2,signed
#define NPOS   78     // nonneg levels: 0 + 77 positive
#define NBUCK  4096   // uniform buckets over y in [0,1); width 2^-12 <= min midpoint spacing
#define BW     (1.0f / 4096.0f)

// native clang vector type: accepted by __builtin_nontemporal_load/store
typedef float vfloat4 __attribute__((ext_vector_type(4)));

// Bit-exact vs reference (proven R9-R11):
//   xc = clamp(x,-a,a); xn = xc * fl(1/a); y = |xn|; neg = xn<0
//   bucket b = floor(y*4096) (exact, pow2); j = sJ[b]; pair = sPair[j]
//   d0=|y-pr.x|, d1=|pr.y-y|; up = neg ? d0>=d1 : d0>d1; q = sign-applied pick
//   out = q*a + (x-xc)   (pass-through STE tail beyond clip)
__device__ __forceinline__ float quant_one(
    float xe, float a, float r,
    const float2* __restrict__ sPair,
    const unsigned char* __restrict__ sJ)
{
#pragma clang fp contract(off)
    const float xc = fminf(fmaxf(xe, -a), a);
    const float xn = __fmul_rn(xc, r);          // reciprocal-multiply (== ref)
    const float y  = fabsf(xn);
    const bool  neg = (xn < 0.0f);
    const float u = __fmul_rn(y, 4096.0f);      // exact (power-of-two scale)
    int b = (int)u;                              // trunc == floor (y >= 0)
    b = min(b, NBUCK - 1);
    const int j = sJ[b];
    const float2 pr = sPair[j];
    const float d0 = fabsf(__fsub_rn(y, pr.x));  // == ref |xn-l0| bits
    const float d1 = fabsf(__fsub_rn(pr.y, y));  // == ref |xn-l1| bits
    const bool up = neg ? (d0 >= d1) : (d0 > d1);
    const float qm = up ? pr.y : pr.x;
    const float q  = neg ? -qm : qm;
    return __fadd_rn(__fmul_rn(q, a), __fsub_rn(xe, xc));
}

__device__ __forceinline__ vfloat4 quant_vec(
    vfloat4 xv, float a, float r,
    const float2* __restrict__ sPair,
    const unsigned char* __restrict__ sJ)
{
    vfloat4 ov;
    ov.x = quant_one(xv.x, a, r, sPair, sJ);
    ov.y = quant_one(xv.y, a, r, sPair, sJ);
    ov.z = quant_one(xv.z, a, r, sPair, sJ);
    ov.w = quant_one(xv.w, a, r, sPair, sJ);
    return ov;
}

__global__ __launch_bounds__(256) void apot_quant_lut(
    const float* __restrict__ x,
    const float* __restrict__ alpha_p,
    const float* __restrict__ levels,
    float* __restrict__ out,
    long long n_elem, float g)
{
#pragma clang fp contract(off)
    __shared__ float  sP[NPOS];
    __shared__ float  sM[NPOS];          // midpoints m[0..76] + huge pad at [77]
    __shared__ float2 sPair[NPOS + 1];   // clamped consecutive pairs, idx 0..78
    __shared__ unsigned char sJ[NBUCK];  // bucket -> pair index j in [1,78]

    const int t = threadIdx.x;
    if (t < NPOS) sP[t] = levels[(LEV_N - NPOS) + t];
    __syncthreads();
    if (t < NPOS - 1)
        sM[t] = __fmul_rn(__fadd_rn(sP[t], sP[t + 1]), 0.5f);  // exact in f32
    if (t == NPOS - 1) sM[t] = 3.0e38f;
    if (t <= NPOS) {
        int j0 = max(t - 1, 0);
        int j1 = min(t, NPOS - 1);
        sPair[t] = make_float2(sP[j0], sP[j1]);
    }
    __syncthreads();

    // Build sJ: monotone walk, 16 buckets per thread.
    {
        const int b0 = t * (NBUCK / 256);
        const float s0 = (float)b0 * BW;             // exact
        int lo = 0, hi = NPOS - 1;                   // count over m[0..76]
        #pragma unroll
        for (int it = 0; it < 7; ++it) {             // cnt = #(m < s0)
            int mid = (lo + hi) >> 1;
            bool c = sM[mid] < s0;
            lo = c ? mid + 1 : lo;
            hi = c ? hi : mid;
        }
        int cnt = lo;
        for (int k = 0; k < NBUCK / 256; ++k) {
            float s = (float)(b0 + k) * BW;          // exact
            while (cnt < NPOS - 1 && sM[cnt] < s) ++cnt;
            sJ[b0 + k] = (unsigned char)(cnt + 1);
        }
    }
    __syncthreads();

    // a = max((alpha - alpha*g) + alpha*g, EPS), f32 ops, no contraction
    const float alpha = alpha_p[0];
    const float ag = __fmul_rn(alpha, g);
    const float a  = fmaxf(__fadd_rn(__fsub_rn(alpha, ag), ag), 1e-8f);
    const float r  = 1.0f / a;

    const long long nvec = n_elem >> 2;
    const long long gid = (long long)blockIdx.x * blockDim.x + t;
    const long long stride = (long long)gridDim.x * blockDim.x;
    const vfloat4* __restrict__ xv4 = reinterpret_cast<const vfloat4*>(x);
    vfloat4* __restrict__ ov4 = reinterpret_cast<vfloat4*>(out);

    // 2x unrolled grid-stride: two independent coalesced streams in flight,
    // non-temporal (streaming) loads/stores — data has zero reuse.
    long long idx = gid;
    for (; idx + stride < nvec; idx += 2 * stride) {
        vfloat4 v0 = __builtin_nontemporal_load(&xv4[idx]);
        vfloat4 v1 = __builtin_nontemporal_load(&xv4[idx + stride]);
        vfloat4 o0 = quant_vec(v0, a, r, sPair, sJ);
        vfloat4 o1 = quant_vec(v1, a, r, sPair, sJ);
        __builtin_nontemporal_store(o0, &ov4[idx]);
        __builtin_nontemporal_store(o1, &ov4[idx + stride]);
    }
    for (; idx < nvec; idx += stride) {
        vfloat4 v0 = __builtin_nontemporal_load(&xv4[idx]);
        vfloat4 o0 = quant_vec(v0, a, r, sPair, sJ);
        __builtin_nontemporal_store(o0, &ov4[idx]);
    }
    for (long long i = (nvec << 2) + gid; i < n_elem; i += stride)
        out[i] = quant_one(x[i], a, r, sPair, sJ);
}

// ---- fallback: proven R9 kernel (absmax 0.0), used if n_levels != 155 ----
#define LEV_MAX 256
__global__ __launch_bounds__(256) void apot_quant_kernel(
    const float* __restrict__ x,
    const float* __restrict__ alpha_p,
    const float* __restrict__ levels,
    float* __restrict__ out,
    int n_levels, long long n_elem, float g)
{
#pragma clang fp contract(off)
    __shared__ float s_lev[LEV_MAX];
    const int t = threadIdx.x;
    for (int i = t; i < LEV_MAX; i += blockDim.x)
        s_lev[i] = (i < n_levels) ? levels[i] : 3.0e38f;
    __syncthreads();
    const float alpha = alpha_p[0];
    const float ag = __fmul_rn(alpha, g);
    const float a  = fmaxf(__fadd_rn(__fsub_rn(alpha, ag), ag), 1e-8f);
    const float r = 1.0f / a;
    const int nm1 = n_levels - 1;
    const long long gid = (long long)blockIdx.x * blockDim.x + t;
    const long long stride = (long long)gridDim.x * blockDim.x;
    for (long long i = gid; i < n_elem; i += stride) {
        const float xe = x[i];
        const float xc = fminf(fmaxf(xe, -a), a);
        const float xn = __fmul_rn(xc, r);
        int lo = 0, hi = n_levels;
        for (int it = 0; it < 8; ++it) {
            int mid = (lo + hi) >> 1;
            bool cc = s_lev[mid] < xn;
            lo = cc ? mid + 1 : lo;
            hi = cc ? hi : mid;
        }
        int p0 = min(max(lo - 1, 0), nm1);
        int p1 = min(lo, nm1);
        float l0 = s_lev[p0];
        float l1 = s_lev[p1];
        float q = (fabsf(__fsub_rn(xn, l0)) > fabsf(__fsub_rn(xn, l1))) ? l1 : l0;
        out[i] = __fadd_rn(__fmul_rn(q, a), __fsub_rn(xe, xc));
    }
}

extern "C" void kernel_launch(void* const* d_in, const int* in_sizes, int n_in,
                              void* d_out, int out_size, void* d_ws, size_t ws_size,
                              hipStream_t stream) {
    const float* x      = (const float*)d_in[0];
    const float* alpha  = (const float*)d_in[1];
    const float* levels = (const float*)d_in[2];
    float* out = (float*)d_out;

    const long long n_elem = (long long)in_sizes[0];
    const int n_levels = in_sizes[2];
    const float g = (float)(1.0 / sqrt((double)n_elem));

    const int block = 256;
    if (n_levels == LEV_N) {
        long long nvec = n_elem >> 2;
        long long want = (nvec + block - 1) / block;
        int grid = (int)(want < 2048 ? (want > 0 ? want : 1) : 2048);
        apot_quant_lut<<<grid, block, 0, stream>>>(x, alpha, levels, out,
                                                   n_elem, g);
    } else {
        long long want = (n_elem + block - 1) / block;
        int grid = (int)(want < 2048 ? (want > 0 ? want : 1) : 2048);
        apot_quant_kernel<<<grid, block, 0, stream>>>(x, alpha, levels, out,
                                                      n_levels, n_elem, g);
    }
}

// Round 14
// 103.834 us; speedup vs baseline: 1.2664x; 1.0330x over previous
//
#include <hip/hip_runtime.h>
#include <math.h>

#define LEV_N  155    // n_levels for bits=8,k=2,signed
#define NPOS   78     // nonneg levels: 0 + 77 positive
#define NBUCK  4096   // uniform buckets over y in [0,1); width 2^-12 <= min midpoint spacing
#define BW     (1.0f / 4096.0f)
#define BLK    512    // 512-thr blocks: 4 blocks/CU x 34KB LDS = 136KB, 32 waves/CU

// native clang vector type: accepted by __builtin_nontemporal_load/store
typedef float vfloat4 __attribute__((ext_vector_type(4)));

// Bit-exact vs reference (proven R9-R13):
//   xc = clamp(x,-a,a); xn = xc * fl(1/a); y = |xn|; neg = xn<0
//   b = floor(y*4096) (exact, pow2); pr = sLUT[b] (== sPair[j(b)], proven R11)
//   d0=|y-pr.x|, d1=|pr.y-y|; up = neg ? d0>=d1 : d0>d1; q = sign-applied pick
//   out = q*a + (x-xc)   (pass-through STE tail beyond clip)
__device__ __forceinline__ float quant_one(
    float xe, float a, float r,
    const float2* __restrict__ sLUT)
{
#pragma clang fp contract(off)
    const float xc = fminf(fmaxf(xe, -a), a);
    const float xn = __fmul_rn(xc, r);          // reciprocal-multiply (== ref)
    const float y  = fabsf(xn);
    const bool  neg = (xn < 0.0f);
    const float u = __fmul_rn(y, 4096.0f);      // exact (power-of-two scale)
    int b = (int)u;                              // trunc == floor (y >= 0)
    b = min(b, NBUCK - 1);
    const float2 pr = sLUT[b];                   // ONE independent LDS b64
    const float d0 = fabsf(__fsub_rn(y, pr.x));  // == ref |xn-l0| bits
    const float d1 = fabsf(__fsub_rn(pr.y, y));  // == ref |xn-l1| bits
    const bool up = neg ? (d0 >= d1) : (d0 > d1);
    const float qm = up ? pr.y : pr.x;
    const float q  = neg ? -qm : qm;
    return __fadd_rn(__fmul_rn(q, a), __fsub_rn(xe, xc));
}

__device__ __forceinline__ vfloat4 quant_vec(
    vfloat4 xv, float a, float r,
    const float2* __restrict__ sLUT)
{
    vfloat4 ov;
    ov.x = quant_one(xv.x, a, r, sLUT);
    ov.y = quant_one(xv.y, a, r, sLUT);
    ov.z = quant_one(xv.z, a, r, sLUT);
    ov.w = quant_one(xv.w, a, r, sLUT);
    return ov;
}

__global__ __launch_bounds__(BLK) void apot_quant_lut(
    const float* __restrict__ x,
    const float* __restrict__ alpha_p,
    const float* __restrict__ levels,
    float* __restrict__ out,
    long long n_elem, float g)
{
#pragma clang fp contract(off)
    __shared__ float  sP[NPOS];
    __shared__ float  sM[NPOS];          // midpoints m[0..76] + huge pad at [77]
    __shared__ float2 sPair[NPOS + 1];   // clamped consecutive pairs, idx 0..78
    __shared__ float2 sLUT[NBUCK];       // bucket -> (l0,l1) pair, 32 KB

    const int t = threadIdx.x;
    if (t < NPOS) sP[t] = levels[(LEV_N - NPOS) + t];
    __syncthreads();
    if (t < NPOS - 1)
        sM[t] = __fmul_rn(__fadd_rn(sP[t], sP[t + 1]), 0.5f);  // exact in f32
    if (t == NPOS - 1) sM[t] = 3.0e38f;
    if (t <= NPOS) {
        int j0 = max(t - 1, 0);
        int j1 = min(t, NPOS - 1);
        sPair[t] = make_float2(sP[j0], sP[j1]);
    }
    __syncthreads();

    // Build sLUT: monotone walk, NBUCK/BLK = 8 buckets per thread.
    // j(b) = 1 + #(midpoints < b*BW); sLUT[b] = sPair[j(b)] (== R11 semantics).
    {
        const int b0 = t * (NBUCK / BLK);
        const float s0 = (float)b0 * BW;             // exact
        int lo = 0, hi = NPOS - 1;                   // count over m[0..76]
        #pragma unroll
        for (int it = 0; it < 7; ++it) {             // cnt = #(m < s0)
            int mid = (lo + hi) >> 1;
            bool c = sM[mid] < s0;
            lo = c ? mid + 1 : lo;
            hi = c ? hi : mid;
        }
        int cnt = lo;
        for (int k = 0; k < NBUCK / BLK; ++k) {
            float s = (float)(b0 + k) * BW;          // exact
            while (cnt < NPOS - 1 && sM[cnt] < s) ++cnt;
            sLUT[b0 + k] = sPair[cnt + 1];
        }
    }
    __syncthreads();

    // a = max((alpha - alpha*g) + alpha*g, EPS), f32 ops, no contraction
    const float alpha = alpha_p[0];
    const float ag = __fmul_rn(alpha, g);
    const float a  = fmaxf(__fadd_rn(__fsub_rn(alpha, ag), ag), 1e-8f);
    const float r  = 1.0f / a;

    const long long nvec = n_elem >> 2;
    const long long gid = (long long)blockIdx.x * blockDim.x + t;
    const long long stride = (long long)gridDim.x * blockDim.x;
    const vfloat4* __restrict__ xv4 = reinterpret_cast<const vfloat4*>(x);
    vfloat4* __restrict__ ov4 = reinterpret_cast<vfloat4*>(out);

    // 2x unrolled grid-stride, non-temporal: two independent streams in flight.
    long long idx = gid;
    for (; idx + stride < nvec; idx += 2 * stride) {
        vfloat4 v0 = __builtin_nontemporal_load(&xv4[idx]);
        vfloat4 v1 = __builtin_nontemporal_load(&xv4[idx + stride]);
        vfloat4 o0 = quant_vec(v0, a, r, sLUT);
        vfloat4 o1 = quant_vec(v1, a, r, sLUT);
        __builtin_nontemporal_store(o0, &ov4[idx]);
        __builtin_nontemporal_store(o1, &ov4[idx + stride]);
    }
    for (; idx < nvec; idx += stride) {
        vfloat4 v0 = __builtin_nontemporal_load(&xv4[idx]);
        vfloat4 o0 = quant_vec(v0, a, r, sLUT);
        __builtin_nontemporal_store(o0, &ov4[idx]);
    }
    for (long long i = (nvec << 2) + gid; i < n_elem; i += stride)
        out[i] = quant_one(x[i], a, r, sLUT);
}

// ---- fallback: proven R9 kernel (absmax 0.0), used if n_levels != 155 ----
#define LEV_MAX 256
__global__ __launch_bounds__(256) void apot_quant_kernel(
    const float* __restrict__ x,
    const float* __restrict__ alpha_p,
    const float* __restrict__ levels,
    float* __restrict__ out,
    int n_levels, long long n_elem, float g)
{
#pragma clang fp contract(off)
    __shared__ float s_lev[LEV_MAX];
    const int t = threadIdx.x;
    for (int i = t; i < LEV_MAX; i += blockDim.x)
        s_lev[i] = (i < n_levels) ? levels[i] : 3.0e38f;
    __syncthreads();
    const float alpha = alpha_p[0];
    const float ag = __fmul_rn(alpha, g);
    const float a  = fmaxf(__fadd_rn(__fsub_rn(alpha, ag), ag), 1e-8f);
    const float r = 1.0f / a;
    const int nm1 = n_levels - 1;
    const long long gid = (long long)blockIdx.x * blockDim.x + t;
    const long long stride = (long long)gridDim.x * blockDim.x;
    for (long long i = gid; i < n_elem; i += stride) {
        const float xe = x[i];
        const float xc = fminf(fmaxf(xe, -a), a);
        const float xn = __fmul_rn(xc, r);
        int lo = 0, hi = n_levels;
        for (int it = 0; it < 8; ++it) {
            int mid = (lo + hi) >> 1;
            bool cc = s_lev[mid] < xn;
            lo = cc ? mid + 1 : lo;
            hi = cc ? hi : mid;
        }
        int p0 = min(max(lo - 1, 0), nm1);
        int p1 = min(lo, nm1);
        float l0 = s_lev[p0];
        float l1 = s_lev[p1];
        float q = (fabsf(__fsub_rn(xn, l0)) > fabsf(__fsub_rn(xn, l1))) ? l1 : l0;
        out[i] = __fadd_rn(__fmul_rn(q, a), __fsub_rn(xe, xc));
    }
}

extern "C" void kernel_launch(void* const* d_in, const int* in_sizes, int n_in,
                              void* d_out, int out_size, void* d_ws, size_t ws_size,
                              hipStream_t stream) {
    const float* x      = (const float*)d_in[0];
    const float* alpha  = (const float*)d_in[1];
    const float* levels = (const float*)d_in[2];
    float* out = (float*)d_out;

    const long long n_elem = (long long)in_sizes[0];
    const int n_levels = in_sizes[2];
    const float g = (float)(1.0 / sqrt((double)n_elem));

    if (n_levels == LEV_N) {
        long long nvec = n_elem >> 2;
        long long want = (nvec + BLK - 1) / BLK;
        int grid = (int)(want < 1024 ? (want > 0 ? want : 1) : 1024);
        apot_quant_lut<<<grid, BLK, 0, stream>>>(x, alpha, levels, out,
                                                 n_elem, g);
    } else {
        const int block = 256;
        long long want = (n_elem + block - 1) / block;
        int grid = (int)(want < 2048 ? (want > 0 ? want : 1) : 2048);
        apot_quant_kernel<<<grid, block, 0, stream>>>(x, alpha, levels, out,
                                                      n_levels, n_elem, g);
    }
}